// Round 7
// baseline (118.564 us; speedup 1.0000x reference)
//
#include <hip/hip_runtime.h>
#include <math.h>

#define DET 512
#define NA  180
#define OUT 362   // floor(sqrt(512^2/2))
#define RAD 181   // OUT/2
#define OUTSQ (OUT * OUT)
#define NB  4     // batch size (fixed by the problem: x is (4,1,512,180))

#define NSPLIT 12       // angle partitions per tile (all 4 b's fused per block)
#define APB    15       // angles per block (NA / NSPLIT)
#define CHUNK  3        // angle lines staged per barrier (24.7 KB LDS)
#define LQ     514      // float4 quads per staged line (512 data + 2 zero quads)

// ---------------------------------------------------------------------------
// Compile-time tables / weights.
// ---------------------------------------------------------------------------
constexpr double PI_D = 3.14159265358979323846;

constexpr double tsin(double x) {  // |x| <= pi/4
    double x2 = x * x;
    return x * (1.0 + x2 * (-1.0/6 + x2 * (1.0/120 + x2 * (-1.0/5040 +
               x2 * (1.0/362880 + x2 * (-1.0/39916800))))));
}
constexpr double tcos(double x) {  // |x| <= pi/4
    double x2 = x * x;
    return 1.0 + x2 * (-0.5 + x2 * (1.0/24 + x2 * (-1.0/720 +
               x2 * (1.0/40320 + x2 * (-1.0/3628800)))));
}

struct Trig { float c[NA]; float s[NA]; };
constexpr Trig make_trig() {
    Trig t{};
    constexpr double r = PI_D / 180.0;
    for (int k = 0; k < NA; ++k) {
        double c, s;
        if (k <= 45)       { c =  tcos(k * r);          s =  tsin(k * r); }
        else if (k <= 90)  { c =  tsin((90 - k) * r);   s =  tcos((90 - k) * r); }
        else if (k <= 135) { c = -tsin((k - 90) * r);   s =  tcos((k - 90) * r); }
        else               { c = -tcos((180 - k) * r);  s =  tsin((180 - k) * r); }
        t.c[k] = (float)c; t.s[k] = (float)s;
    }
    return t;
}
__device__ constexpr Trig TRIG = make_trig();

// Ramp weight for odd offset m: w(m) = -2/(pi*m)^2; 0 outside [-511,511] or
// for even m.  ONLY used in constexpr context (if constexpr guards) so it
// folds to a 32-bit float literal (R4 lesson: runtime eval = 90 us).
__host__ __device__ constexpr float rampw0(int m) {
    int a = m < 0 ? -m : m;
    if (a > 511 || (a & 1) == 0) return 0.0f;
    double md = (double)a;
    return (float)(-2.0 / (PI_D * PI_D * md * md));
}

// One tap: v = p[R] feeds the 8 accumulators (outputs at +64j) with
// compile-time literal weights.
template<int R>
__device__ __forceinline__ void tap8(const float* __restrict__ p, float* acc) {
    const float v = p[R];
    if constexpr (rampw0(R)       != 0.0f) acc[0] = fmaf(rampw0(R),       v, acc[0]);
    if constexpr (rampw0(R - 64)  != 0.0f) acc[1] = fmaf(rampw0(R - 64),  v, acc[1]);
    if constexpr (rampw0(R - 128) != 0.0f) acc[2] = fmaf(rampw0(R - 128), v, acc[2]);
    if constexpr (rampw0(R - 192) != 0.0f) acc[3] = fmaf(rampw0(R - 192), v, acc[3]);
    if constexpr (rampw0(R - 256) != 0.0f) acc[4] = fmaf(rampw0(R - 256), v, acc[4]);
    if constexpr (rampw0(R - 320) != 0.0f) acc[5] = fmaf(rampw0(R - 320), v, acc[5]);
    if constexpr (rampw0(R - 384) != 0.0f) acc[6] = fmaf(rampw0(R - 384), v, acc[6]);
    if constexpr (rampw0(R - 448) != 0.0f) acc[7] = fmaf(rampw0(R - 448), v, acc[7]);
}

// Straight-line sweep over odd offsets R, R+2, ..., REND.
template<int R, int REND>
__device__ __forceinline__ void sweep8(const float* __restrict__ p, float* acc) {
    if constexpr (R <= REND) {
        tap8<R>(p, acc);
        sweep8<R + 2, REND>(p, acc);
    }
}

// ---------------------------------------------------------------------------
// Kernel 1: ramp filter, literal-weight tap-sharing, 8 outputs x 8 eighths.
// Block = 512 threads = 1 (b, angle) line; t = tid&63 owns the 8 outputs
// t+64j; e = tid>>6 sweeps one 92-tap eighth of the odd-offset window
// [-511, 959]; eighths combined via an LDS reduction.  92 ds_read_b32 per
// thread (R6 variant: 140) with the FMA count invariant (256/thread).
// Output layout: ft[a][d][b] (batch-interleaved float4 per detector bin).
// ---------------------------------------------------------------------------
__global__ __launch_bounds__(512) void ramp_filter_kernel(
        const float* __restrict__ x, float* __restrict__ ft) {
    const int a   = blockIdx.x;
    const int b   = blockIdx.y;
    const int tid = threadIdx.x;        // 0..511
    const int t   = tid & 63;           // output-thread id
    const int e   = tid >> 6;           // window eighth 0..7 (= wave id)

    __shared__ float xs[3 * DET];       // [0,512) zeros | data | [1024,1536) zeros
    __shared__ float red[7][8][64];     // eighth 1..7 partial accumulators

    // stage + zero pads (x is (B,1,DET,NA): strided column read, L2-served)
    xs[tid]        = 0.0f;
    xs[1024 + tid] = 0.0f;
    xs[512 + tid]  = x[(b * DET + tid) * NA + a];
    __syncthreads();

    const float* p = xs + 512 + t;
    float acc[8] = {0.0f, 0.0f, 0.0f, 0.0f, 0.0f, 0.0f, 0.0f, 0.0f};

    if (e == 0) {
        #pragma unroll
        for (int j = 0; j < 8; ++j) acc[j] = 0.5f * p[64 * j];  // center taps
        sweep8<-511, -329>(p, acc);
    } else if (e == 1) { sweep8<-327, -145>(p, acc);
    } else if (e == 2) { sweep8<-143,   39>(p, acc);
    } else if (e == 3) { sweep8<  41,  223>(p, acc);
    } else if (e == 4) { sweep8< 225,  407>(p, acc);
    } else if (e == 5) { sweep8< 409,  591>(p, acc);
    } else if (e == 6) { sweep8< 593,  775>(p, acc);
    } else             { sweep8< 777,  959>(p, acc); }

    if (e != 0) {
        #pragma unroll
        for (int j = 0; j < 8; ++j) red[e - 1][j][t] = acc[j];
    }
    __syncthreads();

    if (e == 0) {
        // batch-interleaved store: ft[(a*DET + d)*4 + b], d = t + 64j
        float* ob = ft + ((size_t)a * DET + t) * NB + b;
        #pragma unroll
        for (int j = 0; j < 8; ++j) {
            float s = acc[j];
            #pragma unroll
            for (int q7 = 0; q7 < 7; ++q7) s += red[q7][j][t];
            ob[(size_t)(64 * j) * NB] = s;
        }
    }
}

// ---------------------------------------------------------------------------
// Kernel 2: backprojection, batch-of-4 fused, occupancy-restored.
// Grid (6,12,NSPLIT); 64x32 pixel tile; 512 threads; 4 cols/thread
// (+0/+16/+32/+48) x 4 images.  One pair of ds_read_b128 serves 4 interps;
// index math batch-invariant.  CHUNK=3 -> 24.7 KB LDS -> 3-4 blocks/CU
// (R6's 41.5 KB allowed only ~2 -> 23% occupancy -> latency-bound 45 us).
// Zero quads at [512],[513] catch the pos>511 guard; guarded-off pixels
// (c>=OUT) may compute garbage but never store it.
// ---------------------------------------------------------------------------
__device__ __forceinline__ void acc4(float4& acc,
        const float4* __restrict__ L, float pos) {
    float pf = floorf(pos);
    float fr = pos - pf;
    int   i0 = (int)pf;                       // valid pixels: 0..511
    const float4* q = (pos > (float)(DET - 1)) ? (L + DET) : (L + i0);
    float4 g0 = q[0];
    float4 g1 = q[1];
    acc.x += fmaf(fr, g1.x - g0.x, g0.x);
    acc.y += fmaf(fr, g1.y - g0.y, g0.y);
    acc.z += fmaf(fr, g1.z - g0.z, g0.z);
    acc.w += fmaf(fr, g1.w - g0.w, g0.w);
}

__global__ __launch_bounds__(512, 6) void backproject_kernel(
        const float4* __restrict__ ftq, float* __restrict__ out) {
    const int sp = blockIdx.z;               // angle partition (b's fused)
    const int r0 = blockIdx.y * 32;
    const int c0 = blockIdx.x * 64;
    const int tid = threadIdx.x;
    const int tx = tid & 15;
    const int ty = tid >> 4;                 // 0..31

    __shared__ float4 lines[CHUNK][LQ];

    // zero sentinel quads at [c][512], [c][513] (never overwritten by staging)
    if (tid < 2 * CHUNK)
        lines[tid >> 1][DET + (tid & 1)] = float4{0.0f, 0.0f, 0.0f, 0.0f};

    // clamp row coordinate for guard rows (r >= OUT); col base c0+tx <= 335
    // is always valid, only the +16m shifts can exceed OUT (stores guarded).
    const float xpr = (float)(min(r0 + ty, OUT - 1) - RAD);   // row coord
    const float ypr = (float)(c0 + tx - RAD);                 // col coord

    float4 A0 = {0,0,0,0}, A1 = {0,0,0,0}, A2 = {0,0,0,0}, A3 = {0,0,0,0};

    for (int rd = 0; rd < APB / CHUNK; ++rd) {
        __syncthreads();
        const float4* g = ftq + (size_t)(sp * APB + rd * CHUNK) * DET;
        #pragma unroll
        for (int k = 0; k < CHUNK; ++k) {           // 3 quads per thread
            int j = tid + k * 512;                  // quad index in chunk
            lines[j >> 9][j & 511] = g[j];
        }
        __syncthreads();

        const int abase = sp * APB + rd * CHUNK;
        #pragma unroll
        for (int i = 0; i < CHUNK; ++i) {
            const float cv = TRIG.c[abase + i];
            const float sv = TRIG.s[abase + i];
            // pos = ypr*cos - xpr*sin + det/2
            float p0 = fmaf(ypr, cv, fmaf(xpr, -sv, 256.0f));
            float p1 = fmaf(16.0f, cv, p0);         // col+16
            float p2 = fmaf(32.0f, cv, p0);         // col+32
            float p3 = fmaf(48.0f, cv, p0);         // col+48
            const float4* L = &lines[i][0];
            acc4(A0, L, p0);
            acc4(A1, L, p1);
            acc4(A2, L, p2);
            acc4(A3, L, p3);
        }
    }

    const float scale = (float)(PI_D / (2.0 * NA));
    const int r = r0 + ty;

#define EMIT(ACC, CC)                                              \
    if (r < OUT && (CC) < OUT) {                                   \
        const int off = r * OUT + (CC);                            \
        atomicAdd(out + off,             (ACC).x * scale);         \
        atomicAdd(out + OUTSQ + off,     (ACC).y * scale);         \
        atomicAdd(out + 2 * OUTSQ + off, (ACC).z * scale);         \
        atomicAdd(out + 3 * OUTSQ + off, (ACC).w * scale);         \
    }
    EMIT(A0, c0 + tx);
    EMIT(A1, c0 + tx + 16);
    EMIT(A2, c0 + tx + 32);
    EMIT(A3, c0 + tx + 48);
#undef EMIT
}

extern "C" void kernel_launch(void* const* d_in, const int* in_sizes, int n_in,
                              void* d_out, int out_size, void* d_ws, size_t ws_size,
                              hipStream_t stream) {
    const float* x = (const float*)d_in[0];
    float* ft  = (float*)d_ws;     // NA*DET*NB*4 = 1.47 MB scratch, b-interleaved
    float* out = (float*)d_out;

    const int B = in_sizes[0] / (DET * NA);   // 4 (problem is fixed at B=4)

    hipMemsetAsync(out, 0, (size_t)out_size * sizeof(float), stream);
    ramp_filter_kernel<<<dim3(NA, B), 512, 0, stream>>>(x, ft);
    backproject_kernel<<<dim3((OUT + 63) / 64, (OUT + 31) / 32, NSPLIT),
                         512, 0, stream>>>((const float4*)ft, out);
}

// Round 8
// 111.162 us; speedup vs baseline: 1.0666x; 1.0666x over previous
//
#include <hip/hip_runtime.h>
#include <math.h>

#define DET 512
#define NA  180
#define OUT 362   // floor(sqrt(512^2/2))
#define RAD 181   // OUT/2
#define OUTSQ (OUT * OUT)
#define NB  4     // batch size (fixed: x is (4,1,512,180))

#define NSPLIT 12       // angle partitions per tile (all 4 b's fused per block)
#define APB    15       // angles per block (NA / NSPLIT)
#define CHUNK  3        // angle lines staged per barrier
#define LSTR   5        // dword stride per detector quad: breaks 16B alignment so
                        // the compiler CANNOT merge per-b loads into ds_read_b128
                        // (R6/R7 lesson: divergent b128 is the slow path); emits
                        // ds_read2_b32 (R5's proven-fast class) instead.
#define LLEN   (514 * LSTR)   // floats per staged line (512 data + 2 sentinel quads)

// ---------------------------------------------------------------------------
// Compile-time tables / weights.
// ---------------------------------------------------------------------------
constexpr double PI_D = 3.14159265358979323846;

constexpr double tsin(double x) {  // |x| <= pi/4
    double x2 = x * x;
    return x * (1.0 + x2 * (-1.0/6 + x2 * (1.0/120 + x2 * (-1.0/5040 +
               x2 * (1.0/362880 + x2 * (-1.0/39916800))))));
}
constexpr double tcos(double x) {  // |x| <= pi/4
    double x2 = x * x;
    return 1.0 + x2 * (-0.5 + x2 * (1.0/24 + x2 * (-1.0/720 +
               x2 * (1.0/40320 + x2 * (-1.0/3628800)))));
}

struct Trig { float c[NA]; float s[NA]; };
constexpr Trig make_trig() {
    Trig t{};
    constexpr double r = PI_D / 180.0;
    for (int k = 0; k < NA; ++k) {
        double c, s;
        if (k <= 45)       { c =  tcos(k * r);          s =  tsin(k * r); }
        else if (k <= 90)  { c =  tsin((90 - k) * r);   s =  tcos((90 - k) * r); }
        else if (k <= 135) { c = -tsin((k - 90) * r);   s =  tcos((k - 90) * r); }
        else               { c = -tcos((180 - k) * r);  s =  tsin((180 - k) * r); }
        t.c[k] = (float)c; t.s[k] = (float)s;
    }
    return t;
}
__device__ constexpr Trig TRIG = make_trig();

// Ramp weight for odd offset m: w(m) = -2/(pi*m)^2; 0 outside [-511,511] or
// even m.  ONLY used in constexpr context so it folds to a 32-bit literal
// (R4 lesson: runtime eval = f64 VALU storm, 90 us).
__host__ __device__ constexpr float rampw0(int m) {
    int a = m < 0 ? -m : m;
    if (a > 511 || (a & 1) == 0) return 0.0f;
    double md = (double)a;
    return (float)(-2.0 / (PI_D * PI_D * md * md));
}

// One tap: v = p[R] feeds the 4 accumulators with compile-time weights.
template<int R>
__device__ __forceinline__ void tap(const float* __restrict__ p,
        float& a0, float& a1, float& a2, float& a3) {
    const float v = p[R];
    if constexpr (rampw0(R)      != 0.0f) a0 = fmaf(rampw0(R),      v, a0);
    if constexpr (rampw0(R - 32) != 0.0f) a1 = fmaf(rampw0(R - 32), v, a1);
    if constexpr (rampw0(R - 64) != 0.0f) a2 = fmaf(rampw0(R - 64), v, a2);
    if constexpr (rampw0(R - 96) != 0.0f) a3 = fmaf(rampw0(R - 96), v, a3);
}

// Straight-line sweep over odd offsets R, R+2, ..., REND.
template<int R, int REND>
__device__ __forceinline__ void sweep(const float* __restrict__ p,
        float& a0, float& a1, float& a2, float& a3) {
    if constexpr (R <= REND) {
        tap<R>(p, a0, a1, a2, a3);
        sweep<R + 2, REND>(p, a0, a1, a2, a3);
    }
}

// ---------------------------------------------------------------------------
// Kernel 1: ramp filter — R5's proven half-split structure (best of the
// half/quarter/eighth variants: ~16 vs ~19 vs ~24 us), store remapped to the
// batch-interleaved ft[a][d][b] layout for the fused backprojector.
// Block = 256 threads = 1 (b, angle) line; t = tid&127 owns outputs
// q, q+32, q+64, q+96 with q = (t&31) + 128*(t>>5); half = tid>>7 sweeps one
// half of the odd-offset window; halves combined via an LDS reduction.
// ---------------------------------------------------------------------------
__global__ __launch_bounds__(256) void ramp_filter_kernel(
        const float* __restrict__ x, float* __restrict__ ft) {
    const int a   = blockIdx.x;
    const int b   = blockIdx.y;
    const int tid = threadIdx.x;        // 0..255
    const int t    = tid & 127;         // output-thread id
    const int half = tid >> 7;          // window half
    const int q = (t & 31) + 128 * (t >> 5);   // base output (covers all 512)

    __shared__ float xs[3 * DET];       // [0,512) zeros | data | [1024,1536) zeros
    __shared__ float red[4 * 128];      // half-1 partial accumulators

    xs[tid]        = 0.0f;
    xs[256 + tid]  = 0.0f;
    xs[1024 + tid] = 0.0f;
    xs[1280 + tid] = 0.0f;
    xs[512 + tid]  = x[(b * DET + tid) * NA + a];
    xs[768 + tid]  = x[(b * DET + 256 + tid) * NA + a];
    __syncthreads();

    const float* p = xs + 512 + q;
    float a0 = 0.0f, a1 = 0.0f, a2 = 0.0f, a3 = 0.0f;

    if (half == 0) {
        a0 = 0.5f * p[0];               // center taps, once
        a1 = 0.5f * p[32];
        a2 = 0.5f * p[64];
        a3 = 0.5f * p[96];
        sweep<-511, 47>(p, a0, a1, a2, a3);
    } else {
        sweep<49, 607>(p, a0, a1, a2, a3);
        red[      t] = a0;
        red[128 + t] = a1;
        red[256 + t] = a2;
        red[384 + t] = a3;
    }
    __syncthreads();

    if (half == 0) {
        // batch-interleaved store: ft[(a*DET + d)*NB + b]
        float* ob = ft + ((size_t)a * DET + q) * NB + b;
        ob[0]           = a0 + red[      t];
        ob[32 * NB]     = a1 + red[128 + t];
        ob[64 * NB]     = a2 + red[256 + t];
        ob[96 * NB]     = a3 + red[384 + t];
    }
}

// ---------------------------------------------------------------------------
// Kernel 2: backprojection, batch-of-4 fused via stride-5 LDS quads.
// Grid (12,12,NSPLIT); 32x32 tile; 256 threads; 4 px/thread x 4 images.
// Index math (pos/floor/frac/addr/guard) computed ONCE per position and
// shared by the 4 images (R6/R7's 4x VALU win, confirmed: 25.6 -> 9.1 us),
// but LDS access stays b32-class: 4x ds_read2_b32 off one shared address
// (R5's proven-fast pattern; avoids divergent ds_read_b128).
// Zero sentinel quads at 512,513 catch the pos>511 guard redirect.
// ---------------------------------------------------------------------------
__device__ __forceinline__ void acc4(float4& acc,
        const float* __restrict__ L, float pos) {
    float pf = floorf(pos);
    float fr = pos - pf;
    int   i0 = (int)pf;                       // valid pixels: 0..511
    int   di = (pos > (float)(DET - 1)) ? (DET * LSTR) : (i0 * LSTR);
    const float* qp = L + di;
    float g0x = qp[0],        g0y = qp[1],        g0z = qp[2],        g0w = qp[3];
    float g1x = qp[LSTR + 0], g1y = qp[LSTR + 1], g1z = qp[LSTR + 2], g1w = qp[LSTR + 3];
    acc.x += fmaf(fr, g1x - g0x, g0x);
    acc.y += fmaf(fr, g1y - g0y, g0y);
    acc.z += fmaf(fr, g1z - g0z, g0z);
    acc.w += fmaf(fr, g1w - g0w, g0w);
}

__global__ __launch_bounds__(256) void backproject_kernel(
        const float4* __restrict__ ftq, float* __restrict__ out) {
    const int sp = blockIdx.z;               // angle partition (b's fused)
    const int r0 = blockIdx.y * 32;
    const int c0 = blockIdx.x * 32;
    const int tid = threadIdx.x;
    const int tx = tid & 15;
    const int ty = tid >> 4;

    __shared__ float lines[CHUNK][LLEN];     // 3 x 2570 floats = 30.8 KB

    // zero sentinel quads (dwords 512*LSTR .. 513*LSTR+4), never re-staged
    if (tid < CHUNK * 10)
        lines[tid / 10][512 * LSTR + (tid % 10)] = 0.0f;

    // clamp base coordinate for guard pixels (r/c >= OUT); stores guarded.
    const float xpr = (float)(min(r0 + ty, OUT - 1) - RAD);   // row coord
    const float ypr = (float)(min(c0 + tx, OUT - 1) - RAD);   // col coord

    float4 A00 = {0,0,0,0}, A01 = {0,0,0,0}, A10 = {0,0,0,0}, A11 = {0,0,0,0};

    for (int rd = 0; rd < APB / CHUNK; ++rd) {
        __syncthreads();
        const float4* g = ftq + (size_t)(sp * APB + rd * CHUNK) * DET;
        #pragma unroll
        for (int k = 0; k < CHUNK * DET / 256; ++k) {   // 6 quads / thread
            int j = tid + k * 256;                      // quad index in chunk
            float4 v = g[j];
            float* w = &lines[j >> 9][(j & 511) * LSTR];
            w[0] = v.x; w[1] = v.y; w[2] = v.z; w[3] = v.w;
        }
        __syncthreads();

        const int abase = sp * APB + rd * CHUNK;
        #pragma unroll
        for (int i = 0; i < CHUNK; ++i) {
            const float cv = TRIG.c[abase + i];
            const float sv = TRIG.s[abase + i];
            // pos = ypr*cos - xpr*sin + det/2
            float p00 = fmaf(ypr, cv, fmaf(xpr, -sv, 256.0f));
            float p01 = fmaf(16.0f, cv, p00);       // col+16
            float p10 = fmaf(-16.0f, sv, p00);      // row+16
            float p11 = fmaf(-16.0f, sv, p01);      // row+16, col+16
            const float* L = &lines[i][0];
            acc4(A00, L, p00);
            acc4(A01, L, p01);
            acc4(A10, L, p10);
            acc4(A11, L, p11);
        }
    }

    const float scale = (float)(PI_D / (2.0 * NA));
    const int r = r0 + ty;
    const int c = c0 + tx;

#define EMIT(ACC, RR, CC)                                          \
    if ((RR) < OUT && (CC) < OUT) {                                \
        const int off = (RR) * OUT + (CC);                         \
        atomicAdd(out + off,             (ACC).x * scale);         \
        atomicAdd(out + OUTSQ + off,     (ACC).y * scale);         \
        atomicAdd(out + 2 * OUTSQ + off, (ACC).z * scale);         \
        atomicAdd(out + 3 * OUTSQ + off, (ACC).w * scale);         \
    }
    EMIT(A00, r, c);
    EMIT(A01, r, c + 16);
    EMIT(A10, r + 16, c);
    EMIT(A11, r + 16, c + 16);
#undef EMIT
}

extern "C" void kernel_launch(void* const* d_in, const int* in_sizes, int n_in,
                              void* d_out, int out_size, void* d_ws, size_t ws_size,
                              hipStream_t stream) {
    const float* x = (const float*)d_in[0];
    float* ft  = (float*)d_ws;     // NA*DET*NB*4 = 1.47 MB scratch, b-interleaved
    float* out = (float*)d_out;

    const int B = in_sizes[0] / (DET * NA);   // 4 (problem is fixed at B=4)

    hipMemsetAsync(out, 0, (size_t)out_size * sizeof(float), stream);
    ramp_filter_kernel<<<dim3(NA, B), 256, 0, stream>>>(x, ft);
    backproject_kernel<<<dim3((OUT + 31) / 32, (OUT + 31) / 32, NSPLIT),
                         256, 0, stream>>>((const float4*)ft, out);
}